// Round 3
// baseline (214.009 us; speedup 1.0000x reference)
//
#include <hip/hip_runtime.h>
#include <hip/hip_bf16.h>
#include <stdint.h>

// ---------------- types / helpers ----------------
typedef __attribute__((ext_vector_type(8))) short bf16x8;
typedef __attribute__((ext_vector_type(4))) short bf16x4;
typedef __attribute__((ext_vector_type(4))) float f32x4;
typedef __attribute__((ext_vector_type(4))) int   i32x4;

#define DEV static __device__ __forceinline__

DEV float bf2f(short s) {
    unsigned u = ((unsigned)(unsigned short)s) << 16;
    return __builtin_bit_cast(float, u);
}
DEV short f2bf(float f) {  // RNE
    unsigned u = __builtin_bit_cast(unsigned, f);
    unsigned r = u + 0x7fffu + ((u >> 16) & 1u);
    return (short)(r >> 16);
}
DEV unsigned pack2bf(float a, float b) {  // low = a, high = b (v_cvt_pk_bf16_f32)
    __hip_bfloat162 h = __float22bfloat162_rn(make_float2(a, b));
    unsigned u;
    __builtin_memcpy(&u, &h, 4);
    return u;
}

// problem constants
#define NCH 256
#define PTOT 32768
#define NEXP2 (-2.885390081777927f)   // -2*log2(e)

// ws byte offsets
#define WS_WC1B 0
#define WS_WC2B 32768
#define WS_WD1R 65536
#define WS_WR   360448
#define WS_EKT  1540096
#define WS_EN   2719744

// ---------------- prep: weight reorder + bf16 cast ----------------
// Wr  [256][2304] : Wr[o][k*256+n]   = W[o][n][k]
// wd1r[ 64][2304] : wd1r[m][k*256+n] = w_d1[m][n][kh][kw], k=kh*3+kw
// wc1b[ 64][256]  : = w_c1 (bf16);  wc2b[256][64] : = w_c2 (bf16)
__global__ __launch_bounds__(256) void k_prep(const float* __restrict__ W, const float* __restrict__ w_d1,
                                              const float* __restrict__ w_c1, const float* __restrict__ w_c2,
                                              short* __restrict__ Wr, short* __restrict__ wd1r,
                                              short* __restrict__ wc1b, short* __restrict__ wc2b) {
    int t = blockIdx.x * 256 + threadIdx.x;
    if (t < 589824) {
        int o = t / 2304, rr = t - o * 2304;
        int k = rr >> 8, n = rr & 255;
        Wr[t] = f2bf(W[o * 2304 + n * 9 + k]);
    } else if (t < 589824 + 147456) {
        int t2 = t - 589824;
        int m = t2 / 2304, rr = t2 - m * 2304;
        int k = rr >> 8, n = rr & 255;
        wd1r[t2] = f2bf(w_d1[m * 2304 + n * 9 + k]);
    } else if (t < 589824 + 147456 + 16384) {
        int t3 = t - (589824 + 147456);
        wc1b[t3] = f2bf(w_c1[t3]);
    } else if (t < 589824 + 147456 + 32768) {
        int t4 = t - (589824 + 147456 + 16384);
        wc2b[t4] = f2bf(w_c2[t4]);
    }
}

// ---------------- shared x staging ----------------
// xs layout: [ROWS][66][264] bf16; (r, c, ch): c = w+1 (c=0,65 zero pad), ch minor.
// row stride 528 B (16B aligned). Channel-paired b32 writes (cvt_pk).
template<int ROWS>
DEV void stage_xs(short* xs, const float* __restrict__ x, int b, int h0, float scale) {
    const int tid = threadIdx.x;  // 512 threads
    for (int i = tid; i < ROWS * 256; i += 512) {  // zero pads c=0,65 (b32 granularity)
        int r = i >> 8, rem = i & 255;
        int cc = (rem >> 7) ? 65 : 0, ch2 = (rem & 127) * 2;
        *(int*)(xs + (r * 66 + cc) * 264 + ch2) = 0;
    }
    const int w4 = (tid & 15) * 4;
    const int chp = tid >> 4;  // 0..31
    for (int r = 0; r < ROWS; ++r) {
        int hr = h0 + r;
        bool inb = (hr >= 0) && (hr < 64);
        for (int pass = 0; pass < 4; ++pass) {
            int c0 = (pass * 32 + chp) * 2;
            f32x4 v0 = {0.f, 0.f, 0.f, 0.f}, v1 = {0.f, 0.f, 0.f, 0.f};
            if (inb) {
                v0 = *(const f32x4*)(x + (((size_t)(b * 256 + c0)     * 64 + hr) << 6) + w4);
                v1 = *(const f32x4*)(x + (((size_t)(b * 256 + c0 + 1) * 64 + hr) << 6) + w4);
            }
            #pragma unroll
            for (int j = 0; j < 4; ++j)
                *(int*)(xs + (r * 66 + w4 + j + 1) * 264 + c0) = pack2bf(v0[j] * scale, v1[j] * scale);
        }
    }
}

// ---------------- branch kernel: en (= e^{-2c}) and ekT (= e^{-2d}) ----------------
// LDS: xs [3][66][264] 104544 | yc [64][72] bf16 9216 | ydl [64][68] f32 17408
#define BR_YC    104544
#define BR_YD    (BR_YC + 9216)
#define BR_TOTAL (BR_YD + 17408)   // 131168

__global__ __launch_bounds__(512, 1) void k_branch(const float* __restrict__ x,
        const float* __restrict__ b_c1, const float* __restrict__ b_c2,
        const float* __restrict__ b_d1, const float* __restrict__ w_d2, const float* __restrict__ b_d2,
        const short* __restrict__ wc1b, const short* __restrict__ wc2b, const short* __restrict__ wd1r,
        short* __restrict__ en, float* __restrict__ ekT) {
    extern __shared__ char smem[];
    short* xs  = (short*)smem;
    short* yc  = (short*)(smem + BR_YC);
    float* ydl = (float*)(smem + BR_YD);

    const int rw = blockIdx.x;        // 512 blocks, 64 px each
    const int b = rw >> 6, h = rw & 63;
    const int p0 = rw << 6;
    const int tid = threadIdx.x;
    const int lane = tid & 63, wave = tid >> 6;
    const int l16 = lane & 15, lg = lane >> 4;
    const int wn = wave & 3, wm = wave >> 2;   // 2 (M) x 4 (N)

    stage_xs<3>(xs, x, b, h - 1, 1.0f);
    __syncthreads();

    const int cm = wn * 16 + l16;

    // ---- GEMM1: yc[64px][64cm] = relu(x . w_c1^T + b_c1); B direct from global
    {
        f32x4 acc[2] = {};
        const short* wp = wc1b + cm * 256 + lg * 8;
        bf16x8 bp = *(const bf16x8*)(wp);
        #pragma unroll
        for (int s = 0; s < 8; ++s) {
            bf16x8 bc = bp;
            if (s < 7) bp = *(const bf16x8*)(wp + (s + 1) * 32);
            #pragma unroll
            for (int mt = 0; mt < 2; ++mt) {
                bf16x8 afr = *(const bf16x8*)(xs + (66 + (wm * 32 + mt * 16 + l16) + 1) * 264 + s * 32 + lg * 8);
                acc[mt] = __builtin_amdgcn_mfma_f32_16x16x32_bf16(afr, bc, acc[mt], 0, 0, 0);
            }
        }
        float bias = b_c1[cm];
        #pragma unroll
        for (int mt = 0; mt < 2; ++mt)
            #pragma unroll
            for (int r = 0; r < 4; ++r) {
                int px = wm * 32 + mt * 16 + lg * 4 + r;
                float v = acc[mt][r] + bias;
                yc[px * 72 + cm] = f2bf(v > 0.f ? v : 0.f);
            }
    }
    __syncthreads();

    // ---- GEMM2: c[64px][256] = yc . w_c2^T + b_c2 ; en = exp(-2c); B direct global
    {
        f32x4 acc[2][4] = {};
        #pragma unroll
        for (int s = 0; s < 2; ++s) {
            int k0 = s * 32;
            bf16x8 afr[2], bfr[4];
            #pragma unroll
            for (int mt = 0; mt < 2; ++mt)
                afr[mt] = *(const bf16x8*)(yc + (wm * 32 + mt * 16 + l16) * 72 + k0 + lg * 8);
            #pragma unroll
            for (int nt = 0; nt < 4; ++nt)
                bfr[nt] = *(const bf16x8*)(wc2b + (wn * 64 + nt * 16 + l16) * 64 + k0 + lg * 8);
            #pragma unroll
            for (int mt = 0; mt < 2; ++mt)
                #pragma unroll
                for (int nt = 0; nt < 4; ++nt)
                    acc[mt][nt] = __builtin_amdgcn_mfma_f32_16x16x32_bf16(afr[mt], bfr[nt], acc[mt][nt], 0, 0, 0);
        }
        #pragma unroll
        for (int nt = 0; nt < 4; ++nt) {
            int nc = wn * 64 + nt * 16 + l16;
            float bias = b_c2[nc];
            #pragma unroll
            for (int mt = 0; mt < 2; ++mt)
                #pragma unroll
                for (int r = 0; r < 4; ++r) {
                    int px = wm * 32 + mt * 16 + lg * 4 + r;
                    float cv = acc[mt][nt][r] + bias;
                    en[(size_t)(p0 + px) * 256 + nc] = f2bf(exp2f(NEXP2 * cv));
                }
        }
    }
    // no barrier needed: conv writes ydl (disjoint from yc reads)

    // ---- conv GEMM: yd[64px][64cm] = relu(conv3x3 + b_d1); B direct global
    {
        f32x4 acc[2] = {};
        const short* wp = wd1r + cm * 2304 + lg * 8;
        bf16x8 bp = *(const bf16x8*)(wp);
        for (int kc = 0; kc < 72; ++kc) {
            bf16x8 bc = bp;
            int cc = (kc < 71) ? kc + 1 : 71;
            bp = *(const bf16x8*)(wp + cc * 32);
            int k = kc >> 3, n0 = (kc & 7) << 5;
            int kh = k / 3, kw = k - kh * 3;
            #pragma unroll
            for (int mt = 0; mt < 2; ++mt) {
                bf16x8 afr = *(const bf16x8*)(xs + (kh * 66 + (wm * 32 + mt * 16 + l16) + kw) * 264 + n0 + lg * 8);
                acc[mt] = __builtin_amdgcn_mfma_f32_16x16x32_bf16(afr, bc, acc[mt], 0, 0, 0);
            }
        }
        float bias = b_d1[cm];
        #pragma unroll
        for (int mt = 0; mt < 2; ++mt)
            #pragma unroll
            for (int r = 0; r < 4; ++r) {
                int px = wm * 32 + mt * 16 + lg * 4 + r;
                float v = acc[mt][r] + bias;
                ydl[px * 68 + cm] = v > 0.f ? v : 0.f;
            }
    }
    __syncthreads();

    // ---- d[px][9] = yd . w_d2^T + b_d2 ; ekT[k][p] = exp(-2d)
    for (int t = tid; t < 576; t += 512) {
        int px = t / 9, k = t - px * 9;
        float sum = b_d2[k];
        const float* yr = ydl + px * 68;
        const float* wr = w_d2 + k * 64;
        #pragma unroll 8
        for (int m = 0; m < 64; ++m) sum += yr[m] * wr[m];
        ekT[(size_t)k * PTOT + p0 + px] = exp2f(NEXP2 * sum);
    }
}

// ---------------- final kernel: out = (patches*attn) . W ----------------
// 256 blocks x 128 px (2 rows). LDS: xs [4][66][264] 139392 | ekl [9][128] bf16 2304
// | zl 2 x [128][40] bf16 (10240 each).  Total 162176 B.
#define FN_EK    139392
#define FN_ZL    (FN_EK + 2304)
#define FN_TOTAL (FN_ZL + 20480)   // 162176

DEV void compute_z(short* zbuf, const short* xs, const short* ekl, bf16x8 e8,
                   int c, int zpx, int zq) {
    int k = c >> 3, n0 = (c & 7) << 5;
    int kh = k / 3, kw = k - kh * 3;
    int zr = zpx >> 6, zw = zpx & 63;
    float ekv = bf2f(ekl[k * 128 + zpx]);
    bf16x8 x8 = *(const bf16x8*)(xs + ((zr + kh) * 66 + zw + kw) * 264 + n0 + zq * 8);
    i32x4 zz;
    #pragma unroll
    for (int i = 0; i < 4; ++i) {
        float q0 = __builtin_fmaf(ekv, bf2f(e8[2 * i]),     1.0f);
        float q1 = __builtin_fmaf(ekv, bf2f(e8[2 * i + 1]), 1.0f);
        float z0 = bf2f(x8[2 * i])     * __builtin_amdgcn_rcpf(q0);
        float z1 = bf2f(x8[2 * i + 1]) * __builtin_amdgcn_rcpf(q1);
        zz[i] = pack2bf(z0, z1);
    }
    *(i32x4*)(zbuf + zpx * 40 + zq * 8) = zz;
}

__global__ __launch_bounds__(512, 1) void k_final(const float* __restrict__ x,
        const short* __restrict__ Wr, const short* __restrict__ en, const float* __restrict__ ekT,
        float* __restrict__ out) {
    extern __shared__ char smem[];
    short* xs  = (short*)smem;
    short* ekl = (short*)(smem + FN_EK);
    short* zl0 = (short*)(smem + FN_ZL);
    short* zl1 = zl0 + 5120;
    float* ot  = (float*)smem;   // epilogue reuse: [256][132] f32 = 135168 <= 139392

    const int rw = blockIdx.x;            // 256 blocks
    const int b = rw >> 5, h = (rw & 31) * 2;
    const int p0 = rw << 7;               // 128 px per block
    const int tid = threadIdx.x;
    const int lane = tid & 63, wave = tid >> 6;
    const int l16 = lane & 15, lg = lane >> 4;
    const int wn = wave & 3, wm = wave >> 2;   // 2 (M) x 4 (N)

    stage_xs<4>(xs, x, b, h - 1, 2.0f);   // x pre-scaled by 2: attn = 2*rcp(1+q)
    for (int i = tid; i < 1152; i += 512)
        ekl[i] = f2bf(ekT[(size_t)(i >> 7) * PTOT + p0 + (i & 127)]);

    const int zpx = tid >> 2, zq = tid & 3;
    const short* enp = en + (size_t)(p0 + zpx) * 256 + zq * 8;

    __syncthreads();  // xs + ekl ready

    // prologue: z(0), prefetch en chunk1 and B chunk0
    {
        bf16x8 e0 = *(const bf16x8*)(enp);
        compute_z(zl0, xs, ekl, e0, 0, zpx, zq);
    }
    bf16x8 e_use = *(const bf16x8*)(enp + 32);
    const short* wp0 = Wr + (size_t)(wn * 64 + 0  + l16) * 2304 + lg * 8;
    const short* wp1 = Wr + (size_t)(wn * 64 + 16 + l16) * 2304 + lg * 8;
    const short* wp2 = Wr + (size_t)(wn * 64 + 32 + l16) * 2304 + lg * 8;
    const short* wp3 = Wr + (size_t)(wn * 64 + 48 + l16) * 2304 + lg * 8;
    bf16x8 bcur[4];
    bcur[0] = *(const bf16x8*)(wp0); bcur[1] = *(const bf16x8*)(wp1);
    bcur[2] = *(const bf16x8*)(wp2); bcur[3] = *(const bf16x8*)(wp3);

    f32x4 acc[4][4] = {};
    const int aoff = (wm * 64 + l16) * 40 + lg * 8;

    __syncthreads();  // zl0 ready

    for (int kc = 0; kc < 72; ++kc) {
        short* zread  = (kc & 1) ? zl1 : zl0;
        short* zwrite = (kc & 1) ? zl0 : zl1;
        // prefetches for next step (stay in flight over this step's compute)
        bf16x8 e_next = *(const bf16x8*)(enp + (((kc + 2) & 7) << 5));
        int cc = (kc < 71) ? (kc + 1) : 71;
        bf16x8 bnext[4];
        bnext[0] = *(const bf16x8*)(wp0 + cc * 32); bnext[1] = *(const bf16x8*)(wp1 + cc * 32);
        bnext[2] = *(const bf16x8*)(wp2 + cc * 32); bnext[3] = *(const bf16x8*)(wp3 + cc * 32);
        // z for next step into the other buffer (overlaps other waves' MFMA)
        if (kc < 71) compute_z(zwrite, xs, ekl, e_use, kc + 1, zpx, zq);
        e_use = e_next;
        // MFMA on current buffer
        bf16x8 afr[4];
        #pragma unroll
        for (int mt = 0; mt < 4; ++mt)
            afr[mt] = *(const bf16x8*)(zread + aoff + mt * 640);
        __builtin_amdgcn_s_setprio(1);
        #pragma unroll
        for (int mt = 0; mt < 4; ++mt)
            #pragma unroll
            for (int nt = 0; nt < 4; ++nt)
                acc[mt][nt] = __builtin_amdgcn_mfma_f32_16x16x32_bf16(afr[mt], bcur[nt], acc[mt][nt], 0, 0, 0);
        __builtin_amdgcn_s_setprio(0);
        bcur[0] = bnext[0]; bcur[1] = bnext[1]; bcur[2] = bnext[2]; bcur[3] = bnext[3];
        __syncthreads();
    }

    // epilogue: acc -> LDS [256 o][132 px] f32, then coalesced f32x4 stores
    #pragma unroll
    for (int nt = 0; nt < 4; ++nt) {
        int o = wn * 64 + nt * 16 + l16;
        #pragma unroll
        for (int mt = 0; mt < 4; ++mt)
            #pragma unroll
            for (int r = 0; r < 4; ++r) {
                int px = wm * 64 + mt * 16 + lg * 4 + r;
                ot[o * 132 + px] = acc[mt][nt][r];
            }
    }
    __syncthreads();
    {
        int o = tid >> 1, r2 = tid & 1;
        float* dst = out + (((size_t)b * 256 + o) * 64 + h + r2) * 64;
        const float* srcp = ot + o * 132 + r2 * 64;
        #pragma unroll
        for (int j = 0; j < 16; ++j)
            *(f32x4*)(dst + 4 * j) = *(const f32x4*)(srcp + 4 * j);
    }
}

// ---------------- launcher ----------------
extern "C" void kernel_launch(void* const* d_in, const int* in_sizes, int n_in,
                              void* d_out, int out_size, void* d_ws, size_t ws_size,
                              hipStream_t stream) {
    const float* x    = (const float*)d_in[0];
    const float* w_c1 = (const float*)d_in[1];
    const float* b_c1 = (const float*)d_in[2];
    const float* w_c2 = (const float*)d_in[3];
    const float* b_c2 = (const float*)d_in[4];
    const float* w_d1 = (const float*)d_in[5];
    const float* b_d1 = (const float*)d_in[6];
    const float* w_d2 = (const float*)d_in[7];
    const float* b_d2 = (const float*)d_in[8];
    const float* Wt   = (const float*)d_in[9];
    float* out = (float*)d_out;
    char* ws = (char*)d_ws;

    short* wc1b = (short*)(ws + WS_WC1B);
    short* wc2b = (short*)(ws + WS_WC2B);
    short* wd1r = (short*)(ws + WS_WD1R);
    short* Wr   = (short*)(ws + WS_WR);
    float* ekT  = (float*)(ws + WS_EKT);
    short* en   = (short*)(ws + WS_EN);

    (void)hipFuncSetAttribute((const void*)k_branch, hipFuncAttributeMaxDynamicSharedMemorySize, BR_TOTAL);
    (void)hipFuncSetAttribute((const void*)k_final,  hipFuncAttributeMaxDynamicSharedMemorySize, FN_TOTAL);

    k_prep<<<3008, 256, 0, stream>>>(Wt, w_d1, w_c1, w_c2, Wr, wd1r, wc1b, wc2b);
    k_branch<<<512, 512, BR_TOTAL, stream>>>(x, b_c1, b_c2, b_d1, w_d2, b_d2, wc1b, wc2b, wd1r, en, ekT);
    k_final<<<256, 512, FN_TOTAL, stream>>>(x, Wr, en, ekT, out);
}

// Round 4
// 183.822 us; speedup vs baseline: 1.1642x; 1.1642x over previous
//
#include <hip/hip_runtime.h>
#include <hip/hip_bf16.h>
#include <stdint.h>

// ---------------- types / helpers ----------------
typedef __attribute__((ext_vector_type(8))) short bf16x8;
typedef __attribute__((ext_vector_type(4))) short bf16x4;
typedef __attribute__((ext_vector_type(4))) float f32x4;
typedef __attribute__((ext_vector_type(4))) int   i32x4;

#define DEV static __device__ __forceinline__

DEV float bf2f(short s) {
    unsigned u = ((unsigned)(unsigned short)s) << 16;
    return __builtin_bit_cast(float, u);
}
DEV short f2bf(float f) {  // RNE
    unsigned u = __builtin_bit_cast(unsigned, f);
    unsigned r = u + 0x7fffu + ((u >> 16) & 1u);
    return (short)(r >> 16);
}
DEV unsigned pack2bf(float a, float b) {  // low = a, high = b (v_cvt_pk_bf16_f32)
    __hip_bfloat162 h = __float22bfloat162_rn(make_float2(a, b));
    unsigned u;
    __builtin_memcpy(&u, &h, 4);
    return u;
}

// problem constants
#define NCH 256
#define PTOT 32768
#define NEXP2 (-2.885390081777927f)   // -2*log2(e)

// ws byte offsets
#define WS_WC1B 0
#define WS_WC2B 32768
#define WS_WD1R 65536
#define WS_WR   360448
#define WS_EKT  1540096
#define WS_EN   2719744

// ---------------- prep: weight reorder + bf16 cast ----------------
// Wr  [256][2304] : Wr[o][k*256+n]   = W[o][n][k]
// wd1r[ 64][2304] : wd1r[m][k*256+n] = w_d1[m][n][kh][kw], k=kh*3+kw
// wc1b[ 64][256]  : = w_c1 (bf16);  wc2b[256][64] : = w_c2 (bf16)
__global__ __launch_bounds__(256) void k_prep(const float* __restrict__ W, const float* __restrict__ w_d1,
                                              const float* __restrict__ w_c1, const float* __restrict__ w_c2,
                                              short* __restrict__ Wr, short* __restrict__ wd1r,
                                              short* __restrict__ wc1b, short* __restrict__ wc2b) {
    int t = blockIdx.x * 256 + threadIdx.x;
    if (t < 589824) {
        int o = t / 2304, rr = t - o * 2304;
        int k = rr >> 8, n = rr & 255;
        Wr[t] = f2bf(W[o * 2304 + n * 9 + k]);
    } else if (t < 589824 + 147456) {
        int t2 = t - 589824;
        int m = t2 / 2304, rr = t2 - m * 2304;
        int k = rr >> 8, n = rr & 255;
        wd1r[t2] = f2bf(w_d1[m * 2304 + n * 9 + k]);
    } else if (t < 589824 + 147456 + 16384) {
        int t3 = t - (589824 + 147456);
        wc1b[t3] = f2bf(w_c1[t3]);
    } else if (t < 589824 + 147456 + 32768) {
        int t4 = t - (589824 + 147456 + 16384);
        wc2b[t4] = f2bf(w_c2[t4]);
    }
}

// ---------------- shared x staging ----------------
// xs layout: [ROWS][66][264] bf16; (r, c, ch): c = w+1 (c=0,65 zero pad), ch minor.
// row stride 528 B. col stride 528 B = 132 dwords -> lane stride 4 banks: conflict-free b128.
template<int ROWS>
DEV void stage_xs(short* xs, const float* __restrict__ x, int b, int h0, float scale) {
    const int tid = threadIdx.x;  // 512 threads
    for (int i = tid; i < ROWS * 256; i += 512) {  // zero pads c=0,65 (b32 granularity)
        int r = i >> 8, rem = i & 255;
        int cc = (rem >> 7) ? 65 : 0, ch2 = (rem & 127) * 2;
        *(int*)(xs + (r * 66 + cc) * 264 + ch2) = 0;
    }
    const int w4 = (tid & 15) * 4;
    const int chp = tid >> 4;  // 0..31
    for (int r = 0; r < ROWS; ++r) {
        int hr = h0 + r;
        bool inb = (hr >= 0) && (hr < 64);
        for (int pass = 0; pass < 4; ++pass) {
            int c0 = (pass * 32 + chp) * 2;
            f32x4 v0 = {0.f, 0.f, 0.f, 0.f}, v1 = {0.f, 0.f, 0.f, 0.f};
            if (inb) {
                v0 = *(const f32x4*)(x + (((size_t)(b * 256 + c0)     * 64 + hr) << 6) + w4);
                v1 = *(const f32x4*)(x + (((size_t)(b * 256 + c0 + 1) * 64 + hr) << 6) + w4);
            }
            #pragma unroll
            for (int j = 0; j < 4; ++j)
                *(int*)(xs + (r * 66 + w4 + j + 1) * 264 + c0) = pack2bf(v0[j] * scale, v1[j] * scale);
        }
    }
}

// ---------------- branch kernel: en (= e^{-2c}) and ekT (= e^{-2d}) ----------------
// LDS: xs [3][66][264] 104544 | yc [64][72] bf16 9216 | ydl [64][67] f32 17152
// ent [64][264] bf16 (33792) reuses xs region after conv.
#define BR_YC    104544
#define BR_YD    (BR_YC + 9216)
#define BR_TOTAL (BR_YD + 17152)   // 130912

__global__ __launch_bounds__(512, 1) void k_branch(const float* __restrict__ x,
        const float* __restrict__ b_c1, const float* __restrict__ b_c2,
        const float* __restrict__ b_d1, const float* __restrict__ w_d2, const float* __restrict__ b_d2,
        const short* __restrict__ wc1b, const short* __restrict__ wc2b, const short* __restrict__ wd1r,
        short* __restrict__ en, float* __restrict__ ekT) {
    extern __shared__ char smem[];
    short* xs  = (short*)smem;
    short* yc  = (short*)(smem + BR_YC);
    float* ydl = (float*)(smem + BR_YD);
    short* ent = (short*)smem;   // valid after xs is dead

    const int rw = blockIdx.x;        // 512 blocks, 64 px each
    const int b = rw >> 6, h = rw & 63;
    const int p0 = rw << 6;
    const int tid = threadIdx.x;
    const int lane = tid & 63, wave = tid >> 6;
    const int l16 = lane & 15, lg = lane >> 4;
    const int wn = wave & 3, wm = wave >> 2;   // 2 (M) x 4 (N)

    stage_xs<3>(xs, x, b, h - 1, 1.0f);
    __syncthreads();

    const int cm = wn * 16 + l16;

    // ---- GEMM1: yc[64px][64cm] = relu(x . w_c1^T + b_c1); B direct from global
    {
        f32x4 acc[2] = {};
        const short* wp = wc1b + cm * 256 + lg * 8;
        #pragma unroll
        for (int s = 0; s < 8; ++s) {
            bf16x8 bc = *(const bf16x8*)(wp + s * 32);
            #pragma unroll
            for (int mt = 0; mt < 2; ++mt) {
                bf16x8 afr = *(const bf16x8*)(xs + (66 + (wm * 32 + mt * 16 + l16) + 1) * 264 + s * 32 + lg * 8);
                acc[mt] = __builtin_amdgcn_mfma_f32_16x16x32_bf16(afr, bc, acc[mt], 0, 0, 0);
            }
        }
        float bias = b_c1[cm];
        #pragma unroll
        for (int mt = 0; mt < 2; ++mt)
            #pragma unroll
            for (int r = 0; r < 4; ++r) {
                int px = wm * 32 + mt * 16 + lg * 4 + r;
                float v = acc[mt][r] + bias;
                yc[px * 72 + cm] = f2bf(v > 0.f ? v : 0.f);
            }
    }

    // ---- conv GEMM: yd[64px][64cm] = relu(conv3x3 + b_d1); B global, 2-deep prefetch
    {
        f32x4 acc[2] = {};
        const short* wp = wd1r + cm * 2304 + lg * 8;
        bf16x8 bp0 = *(const bf16x8*)(wp);
        bf16x8 bp1 = *(const bf16x8*)(wp + 32);
        for (int kc = 0; kc < 72; ++kc) {
            bf16x8 bc = bp0;
            bp0 = bp1;
            int c2 = (kc + 2 < 72) ? kc + 2 : 71;
            bp1 = *(const bf16x8*)(wp + c2 * 32);
            int k = kc >> 3, n0 = (kc & 7) << 5;
            int kh = k / 3, kw = k - kh * 3;
            #pragma unroll
            for (int mt = 0; mt < 2; ++mt) {
                bf16x8 afr = *(const bf16x8*)(xs + (kh * 66 + (wm * 32 + mt * 16 + l16) + kw) * 264 + n0 + lg * 8);
                acc[mt] = __builtin_amdgcn_mfma_f32_16x16x32_bf16(afr, bc, acc[mt], 0, 0, 0);
            }
        }
        float bias = b_d1[cm];
        #pragma unroll
        for (int mt = 0; mt < 2; ++mt)
            #pragma unroll
            for (int r = 0; r < 4; ++r) {
                int px = wm * 32 + mt * 16 + lg * 4 + r;
                float v = acc[mt][r] + bias;
                ydl[px * 67 + cm] = v > 0.f ? v : 0.f;
            }
    }
    __syncthreads();   // yc + ydl ready; xs dead -> ent region usable

    // ---- GEMM2: c[64px][256] = yc . w_c2^T + b_c2 ; ent = exp(-2c) (LDS, n-minor)
    {
        f32x4 acc[2][4] = {};
        #pragma unroll
        for (int s = 0; s < 2; ++s) {
            int k0 = s * 32;
            bf16x8 afr[2], bfr[4];
            #pragma unroll
            for (int mt = 0; mt < 2; ++mt)
                afr[mt] = *(const bf16x8*)(yc + (wm * 32 + mt * 16 + l16) * 72 + k0 + lg * 8);
            #pragma unroll
            for (int nt = 0; nt < 4; ++nt)
                bfr[nt] = *(const bf16x8*)(wc2b + (wn * 64 + nt * 16 + l16) * 64 + k0 + lg * 8);
            #pragma unroll
            for (int mt = 0; mt < 2; ++mt)
                #pragma unroll
                for (int nt = 0; nt < 4; ++nt)
                    acc[mt][nt] = __builtin_amdgcn_mfma_f32_16x16x32_bf16(afr[mt], bfr[nt], acc[mt][nt], 0, 0, 0);
        }
        #pragma unroll
        for (int nt = 0; nt < 4; ++nt) {
            int nc = wn * 64 + nt * 16 + l16;
            float bias = b_c2[nc];
            #pragma unroll
            for (int mt = 0; mt < 2; ++mt)
                #pragma unroll
                for (int r = 0; r < 4; ++r) {
                    int px = wm * 32 + mt * 16 + lg * 4 + r;
                    float cv = acc[mt][nt][r] + bias;
                    ent[px * 264 + nc] = f2bf(exp2f(NEXP2 * cv));
                }
        }
    }

    // ---- d[px][9] = yd . w_d2^T + b_d2 ; ekT[k][p] = exp(-2d)  (coalesced px-minor)
    for (int t = tid; t < 576; t += 512) {
        int k = t >> 6, px = t & 63;
        float sum = b_d2[k];
        const float* yr = ydl + px * 67;
        const float* wr = w_d2 + k * 64;
        #pragma unroll 8
        for (int m = 0; m < 64; ++m) sum += yr[m] * wr[m];
        ekT[(size_t)k * PTOT + p0 + px] = exp2f(NEXP2 * sum);
    }
    __syncthreads();   // ent ready

    // ---- coalesced en store: bf16x8 per lane
    for (int i = tid; i < 2048; i += 512) {
        int row = i >> 5, seg = i & 31;
        *(bf16x8*)(en + (size_t)(p0 + row) * 256 + seg * 8) = *(const bf16x8*)(ent + row * 264 + seg * 8);
    }
}

// ---------------- final kernel: out = (patches*attn) . W ----------------
// 256 blocks x 128 px (2 rows), 8 waves (2M x 4N), ZERO barriers in K-loop.
// Each lane builds its own A-fragments in registers (z = 2x * rcp(1 + ek*en)).
// LDS: xs [4][66][264] 139392 | ekl f32 [9][128] 4608.  Total 144000 B.
#define FN_EKL   139392
#define FN_TOTAL (FN_EKL + 4608)   // 144000

__global__ __launch_bounds__(512, 1) void k_final(const float* __restrict__ x,
        const short* __restrict__ Wr, const short* __restrict__ en, const float* __restrict__ ekT,
        float* __restrict__ out) {
    extern __shared__ char smem[];
    short* xs  = (short*)smem;
    float* ekl = (float*)(smem + FN_EKL);
    float* ot  = (float*)smem;   // epilogue reuse: [256][132] f32 = 135168 <= 139392

    const int rw = blockIdx.x;            // 256 blocks
    const int b = rw >> 5, h = (rw & 31) * 2;
    const int p0 = rw << 7;               // 128 px per block
    const int tid = threadIdx.x;
    const int lane = tid & 63, wave = tid >> 6;
    const int l16 = lane & 15, lg = lane >> 4;
    const int wn = wave & 3, wm = wave >> 2;   // 2 (M) x 4 (N)

    stage_xs<4>(xs, x, b, h - 1, 2.0f);   // x pre-scaled by 2: attn = 2*rcp(1+q)
    for (int i = tid; i < 1152; i += 512)
        ekl[i] = ekT[(size_t)(i >> 7) * PTOT + p0 + (i & 127)];
    __syncthreads();   // the ONLY barrier before the epilogue

    // per-lane base pointers: A rows px(mt) = wm*64 + mt*16 + l16 ; B cols o(nt) = wn*64 + nt*16 + l16
    const short* enp0 = en + (size_t)(p0 + wm * 64 + l16) * 256 + lg * 8;   // + mt*4096, + nc*32
    const short* wpb  = Wr + (size_t)(wn * 64 + l16) * 2304 + lg * 8;       // + nt*36864, + (k*256+n0)

    bf16x8 ecur[4], enx[4], bcur[4], bnx[4];
    #pragma unroll
    for (int mt = 0; mt < 4; ++mt) ecur[mt] = *(const bf16x8*)(enp0 + mt * 4096);
    #pragma unroll
    for (int nt = 0; nt < 4; ++nt) bcur[nt] = *(const bf16x8*)(wpb + nt * 36864);

    f32x4 acc[4][4] = {};

    for (int nc = 0; nc < 8; ++nc) {      // n-outer: en chunk reused across 9 k-steps
        const int n0 = nc * 32;
        const int ncn = (nc + 1) & 7;
        #pragma unroll
        for (int mt = 0; mt < 4; ++mt)    // prefetch next chunk's en (9-step lead)
            enx[mt] = *(const bf16x8*)(enp0 + mt * 4096 + ncn * 32);
        #pragma unroll
        for (int k = 0; k < 9; ++k) {
            const int kh = k / 3, kw = k - kh * 3;
            const int knext = (k < 8) ? ((k + 1) * 256 + n0) : (ncn * 32);
            #pragma unroll
            for (int nt = 0; nt < 4; ++nt)   // B prefetch 1 step ahead
                bnx[nt] = *(const bf16x8*)(wpb + nt * 36864 + knext);
            // wave-private A fragments
            bf16x8 afr[4];
            #pragma unroll
            for (int mt = 0; mt < 4; ++mt) {
                const int px = wm * 64 + mt * 16 + l16;
                bf16x8 x8 = *(const bf16x8*)(xs + ((wm + kh) * 66 + mt * 16 + l16 + kw) * 264 + n0 + lg * 8);
                float ekv = ekl[k * 128 + px];
                bf16x8 e8 = ecur[mt];
                i32x4 zz;
                #pragma unroll
                for (int i = 0; i < 4; ++i) {
                    float q0 = __builtin_fmaf(ekv, bf2f(e8[2 * i]),     1.0f);
                    float q1 = __builtin_fmaf(ekv, bf2f(e8[2 * i + 1]), 1.0f);
                    float z0 = bf2f(x8[2 * i])     * __builtin_amdgcn_rcpf(q0);
                    float z1 = bf2f(x8[2 * i + 1]) * __builtin_amdgcn_rcpf(q1);
                    zz[i] = pack2bf(z0, z1);
                }
                afr[mt] = __builtin_bit_cast(bf16x8, zz);
            }
            __builtin_amdgcn_s_setprio(1);
            #pragma unroll
            for (int mt = 0; mt < 4; ++mt)
                #pragma unroll
                for (int nt = 0; nt < 4; ++nt)
                    acc[mt][nt] = __builtin_amdgcn_mfma_f32_16x16x32_bf16(afr[mt], bcur[nt], acc[mt][nt], 0, 0, 0);
            __builtin_amdgcn_s_setprio(0);
            #pragma unroll
            for (int nt = 0; nt < 4; ++nt) bcur[nt] = bnx[nt];
        }
        #pragma unroll
        for (int mt = 0; mt < 4; ++mt) ecur[mt] = enx[mt];
    }

    // epilogue: acc -> LDS [256 o][132 px] f32, then coalesced stores (256B/lane)
    __syncthreads();
    #pragma unroll
    for (int nt = 0; nt < 4; ++nt) {
        int o = wn * 64 + nt * 16 + l16;
        #pragma unroll
        for (int mt = 0; mt < 4; ++mt)
            #pragma unroll
            for (int r = 0; r < 4; ++r) {
                int px = wm * 64 + mt * 16 + lg * 4 + r;
                ot[o * 132 + px] = acc[mt][nt][r];
            }
    }
    __syncthreads();
    {
        int o = tid >> 1, r2 = tid & 1;
        float* dst = out + (((size_t)b * 256 + o) * 64 + h + r2) * 64;
        const float* srcp = ot + o * 132 + r2 * 64;
        #pragma unroll
        for (int j = 0; j < 16; ++j)
            *(f32x4*)(dst + 4 * j) = *(const f32x4*)(srcp + 4 * j);
    }
}

// ---------------- launcher ----------------
extern "C" void kernel_launch(void* const* d_in, const int* in_sizes, int n_in,
                              void* d_out, int out_size, void* d_ws, size_t ws_size,
                              hipStream_t stream) {
    const float* x    = (const float*)d_in[0];
    const float* w_c1 = (const float*)d_in[1];
    const float* b_c1 = (const float*)d_in[2];
    const float* w_c2 = (const float*)d_in[3];
    const float* b_c2 = (const float*)d_in[4];
    const float* w_d1 = (const float*)d_in[5];
    const float* b_d1 = (const float*)d_in[6];
    const float* w_d2 = (const float*)d_in[7];
    const float* b_d2 = (const float*)d_in[8];
    const float* Wt   = (const float*)d_in[9];
    float* out = (float*)d_out;
    char* ws = (char*)d_ws;

    short* wc1b = (short*)(ws + WS_WC1B);
    short* wc2b = (short*)(ws + WS_WC2B);
    short* wd1r = (short*)(ws + WS_WD1R);
    short* Wr   = (short*)(ws + WS_WR);
    float* ekT  = (float*)(ws + WS_EKT);
    short* en   = (short*)(ws + WS_EN);

    (void)hipFuncSetAttribute((const void*)k_branch, hipFuncAttributeMaxDynamicSharedMemorySize, BR_TOTAL);
    (void)hipFuncSetAttribute((const void*)k_final,  hipFuncAttributeMaxDynamicSharedMemorySize, FN_TOTAL);

    k_prep<<<3008, 256, 0, stream>>>(Wt, w_d1, w_c1, w_c2, Wr, wd1r, wc1b, wc2b);
    k_branch<<<512, 512, BR_TOTAL, stream>>>(x, b_c1, b_c2, b_d1, w_d2, b_d2, wc1b, wc2b, wd1r, en, ekT);
    k_final<<<256, 512, FN_TOTAL, stream>>>(x, Wr, en, ekT, out);
}